// Round 9
// baseline (532.350 us; speedup 1.0000x reference)
//
#include <hip/hip_runtime.h>
#include <stdint.h>

typedef _Float16 half8 __attribute__((ext_vector_type(8)));
typedef float f32x4 __attribute__((ext_vector_type(4)));

typedef const __attribute__((address_space(1))) void* gptr_t;
typedef __attribute__((address_space(3))) void* lptr_t;
static __device__ __forceinline__ void gll16(const void* g, void* l) {
  __builtin_amdgcn_global_load_lds((gptr_t)(unsigned long long)g,
                                   (lptr_t)(unsigned int)(unsigned long long)l,
                                   16, 0, 0);
}

// ---- k_pb: B2 = f16(M @ W2 + nn2_b) in (c,i)-chunk-major + riders (cheb+z0, CSR, root).
// B2 layout per layer: j=(c*192+i) for c<5, j=960+k for root; B2[((j>>3)*192 + o)*8 + (j&7)].
__global__ __launch_bounds__(256)
void k_pb(const float* __restrict__ nn2_w, const float* __restrict__ nn2_b,
          const float* __restrict__ eenc_w, const float* __restrict__ eenc_b,
          const float* __restrict__ nn1_w, const float* __restrict__ nn1_b,
          const float* __restrict__ root_w, _Float16* __restrict__ Btl,
          const float* __restrict__ x, const int* __restrict__ ei,
          float* __restrict__ Tx, int* __restrict__ rowptr, int* __restrict__ eord,
          const float* __restrict__ cheb_w, const float* __restrict__ cheb_b,
          _Float16* __restrict__ z0) {
  __shared__ __align__(16) float smem[17344];  // workers: 4x4x4KB tiles + M[960]
  int t = threadIdx.x;
  if (blockIdx.x >= 72) {
    if (blockIdx.x == 72) {
      if (blockIdx.y == 0) {
        // ---- Chebyshev chain (r5/r7/r8-verified) + z0 build ----
        float* cur = smem;
        float* yv = smem + 4096;
        float* deg = yv;
        for (int i = t; i < 1024; i += 256) deg[i] = 0.f;
        __syncthreads();
        for (int e = t; e < 2048; e += 256) atomicAdd(&deg[ei[e]], 1.f);
        __syncthreads();
        float wn[8];
#pragma unroll
        for (int i = 0; i < 8; ++i) {
          int e = t + 256 * i;
          int s = ei[e], d = ei[2048 + e];
          float ds = deg[s], dd = deg[d];
          float a = ds > 0.f ? 1.f / sqrtf(fmaxf(ds, 1.f)) : 0.f;
          float bb = dd > 0.f ? 1.f / sqrtf(fmaxf(dd, 1.f)) : 0.f;
          wn[i] = -a * bb;
        }
        __syncthreads();
        float4 prev[4];
#pragma unroll
        for (int q = 0; q < 4; ++q) {
          int i = t + 256 * q;
          float4 xv = ((const float4*)x)[i];
          ((float4*)cur)[i] = xv;
          ((float4*)Tx)[i] = xv;
        }
        __syncthreads();
        for (int rec = 0; rec < 4; ++rec) {
          for (int i = t; i < 4096; i += 256) yv[i] = 0.f;
          __syncthreads();
#pragma unroll
          for (int i = 0; i < 8; ++i) {
            int e = t + 256 * i;
            int s = ei[e], d = ei[2048 + e];
            float wv = wn[i];
#pragma unroll
            for (int c = 0; c < 4; ++c) atomicAdd(&yv[d * 4 + c], wv * cur[s * 4 + c]);
          }
          __syncthreads();
          float a = rec ? 2.f : 1.f;
#pragma unroll
          for (int q = 0; q < 4; ++q) {
            int i = t + 256 * q;
            float4 y4 = ((float4*)yv)[i];
            float4 c4 = ((float4*)cur)[i];
            float4 n4;
            n4.x = a * y4.x - (rec ? prev[q].x : 0.f);
            n4.y = a * y4.y - (rec ? prev[q].y : 0.f);
            n4.z = a * y4.z - (rec ? prev[q].z : 0.f);
            n4.w = a * y4.w - (rec ? prev[q].w : 0.f);
            prev[q] = c4;
            ((float4*)cur)[i] = n4;
            ((float4*)(Tx + (rec + 1) * 4096))[i] = n4;
          }
          __syncthreads();
        }
        // z0[n][o] = f16(cheb_b[o] + sum_k,c Tx[k][n][c] * cheb_w[(k*4+c)*192+o]), row-major
        for (int n = t; n < 1024; n += 256) {
          float tv[5][4];
#pragma unroll
          for (int k = 0; k < 5; ++k) {
            float4 t4 = ((const float4*)(Tx + k * 4096))[n];
            tv[k][0] = t4.x; tv[k][1] = t4.y; tv[k][2] = t4.z; tv[k][3] = t4.w;
          }
          for (int ob = 0; ob < 24; ++ob) {
            union { _Float16 h[8]; uint4 v; } u8;
#pragma unroll
            for (int jj = 0; jj < 8; ++jj) {
              int o = ob * 8 + jj;
              float acc = cheb_b[o];
#pragma unroll
              for (int k = 0; k < 5; ++k)
#pragma unroll
                for (int c = 0; c < 4; ++c)
                  acc += tv[k][c] * cheb_w[(k * 4 + c) * 192 + o];
              u8.h[jj] = (_Float16)acc;
            }
            *(uint4*)(z0 + (size_t)n * 192 + ob * 8) = u8.v;
          }
        }
      } else if (blockIdx.y == 1) {
        // ---- CSR by dst (verified) ----
        int* cnt = (int*)smem;
        int* rp  = (int*)smem + 1024;
        int* wtot = (int*)smem + 2048;
        int lane = t & 63, wv = t >> 6;
        for (int i = t; i < 1024; i += 256) cnt[i] = 0;
        __syncthreads();
        for (int e = t; e < 2048; e += 256) atomicAdd(&cnt[ei[2048 + e]], 1);
        __syncthreads();
        int c0 = cnt[t * 4], c1 = cnt[t * 4 + 1], c2 = cnt[t * 4 + 2], c3 = cnt[t * 4 + 3];
        int s = c0 + c1 + c2 + c3;
        int inc = s;
#pragma unroll
        for (int off = 1; off < 64; off <<= 1) {
          int u = __shfl_up(inc, off);
          if (lane >= off) inc += u;
        }
        if (lane == 63) wtot[wv] = inc;
        __syncthreads();
        int woff = 0;
#pragma unroll
        for (int j = 0; j < 4; ++j) if (j < wv) woff += wtot[j];
        int excl = woff + inc - s;
        int4 r4; r4.x = excl; r4.y = excl + c0; r4.z = excl + c0 + c1; r4.w = excl + c0 + c1 + c2;
        *(int4*)(rowptr + t * 4) = r4;
        if (t == 0) rowptr[1024] = 2048;
        rp[t * 4] = r4.x; rp[t * 4 + 1] = r4.y; rp[t * 4 + 2] = r4.z; rp[t * 4 + 3] = r4.w;
        __syncthreads();
        for (int e = t; e < 2048; e += 256) {
          int d = ei[2048 + e];
          int slot = atomicAdd(&rp[d], 1);
          eord[slot] = e;
        }
      }
      return;
    }
    // ---- bx==73: root staging, j=960+k ----
    int l = blockIdx.y;
    for (int idx = t; idx < 36864; idx += 256) {
      float vv = root_w[(size_t)l * 36864 + idx];
      int k = idx / 192, o = idx - k * 192;
      int j = 960 + k;
      Btl[(size_t)l * 221184 + ((size_t)(j >> 3) * 192 + o) * 8 + (j & 7)] = (_Float16)vv;
    }
    return;
  }
  // ---- worker: wave-private 4-buf gll16 pipeline over K=192 (r8-verified) ----
  int w = t >> 6, lane = t & 63;
  int l = blockIdx.y;
  int wcol = blockIdx.x * 512 + w * 128;
  const float* W2l = nn2_w + (size_t)l * 7077888;
  char* ldsbase = (char*)smem + w * 16384;
  int rlane = lane >> 5;
  int clane = (lane & 31) << 4;
  float2 nb = *(const float2*)(nn2_b + (size_t)l * 36864 + wcol + 2 * lane);

#define ISSUE(tile)                                                             \
  {                                                                             \
    _Pragma("unroll")                                                           \
    for (int j = 0; j < 4; ++j) {                                               \
      int row = (tile) * 8 + 2 * j + rlane;                                     \
      gll16((const char*)(W2l + (size_t)row * 36864 + wcol) + clane,            \
            ldsbase + ((tile) & 3) * 4096 + j * 1024 + lane * 16);              \
    }                                                                           \
  }

  ISSUE(0); ISSUE(1); ISSUE(2);
  if (t < 192) {
    float a0 = 0.f, a1 = 0.f, a2 = 0.f, a3 = 0.f, a4 = 0.f;
    const float* nw = nn1_w + (size_t)l * 36864 + t;
    for (int k = 0; k < 192; ++k) {
      float nv = nw[(size_t)k * 192];
      a0 += eenc_w[k] * nv;
      a1 += eenc_w[192 + k] * nv;
      a2 += eenc_w[384 + k] * nv;
      a3 += eenc_w[576 + k] * nv;
      a4 += eenc_b[k] * nv;
    }
    smem[16384 + t] = a0; smem[16576 + t] = a1; smem[16768 + t] = a2;
    smem[16960 + t] = a3; smem[17152 + t] = a4 + nn1_b[l * 192 + t];
  }
  __syncthreads();

  float2 a[5] = {};
  const float* Ms = smem + 16384;
  for (int tile = 0; tile < 24; ++tile) {
    if (tile < 21) ISSUE(tile + 3);
    if (tile < 21)       asm volatile("s_waitcnt vmcnt(12)" ::: "memory");
    else if (tile == 21) asm volatile("s_waitcnt vmcnt(8)" ::: "memory");
    else if (tile == 22) asm volatile("s_waitcnt vmcnt(4)" ::: "memory");
    else                 asm volatile("s_waitcnt vmcnt(0)" ::: "memory");
    const float* wb = smem + w * 4096 + (tile & 3) * 1024;
    const float* Mt = Ms + tile * 8;
#pragma unroll
    for (int r = 0; r < 8; ++r) {
      float2 wv = *(const float2*)(wb + r * 128 + 2 * lane);
#pragma unroll
      for (int c = 0; c < 5; ++c) {
        float m = Mt[c * 192 + r];
        a[c].x += m * wv.x; a[c].y += m * wv.y;
      }
    }
  }
#undef ISSUE
  a[4].x += nb.x; a[4].y += nb.y;
  int col = wcol + 2 * lane;
  _Float16* base = Btl + (size_t)l * 221184;
#pragma unroll
  for (int cc = 0; cc < 2; ++cc) {
    int c0 = col + cc;
    int i = c0 / 192, o = c0 - i * 192;
#pragma unroll
    for (int c = 0; c < 5; ++c) {
      int j = c * 192 + i;
      float vv = (cc == 0) ? a[c].x : a[c].y;
      base[((size_t)(j >> 3) * 192 + o) * 8 + (j & 7)] = (_Float16)vv;
    }
  }
}

// ---- k_lyr: per-layer fused {CSR gather -> Gx | GEMM [16x1152]@[1152x192] | +bias+res+LN+relu | out} ----
__global__ __launch_bounds__(256)
void k_lyr(const _Float16* __restrict__ z16in, const _Float16* __restrict__ B2l,
           const int* __restrict__ ei, const float4* __restrict__ eattr4,
           const int* __restrict__ rowptr, const int* __restrict__ eord,
           const float* __restrict__ hp, const float* __restrict__ cbv,
           const float* __restrict__ gg, const float* __restrict__ bb,
           float* __restrict__ ho, _Float16* __restrict__ z16out,
           const float* __restrict__ out_w, const float* __restrict__ out_b,
           float* __restrict__ outp, int l) {
  __shared__ __align__(16) _Float16 A_lds[18432];  // 144 ck x 16 rows x 8
  __shared__ float2 lnred[4][16];
  __shared__ float2 outred[4][16];
  int t = threadIdx.x, w = t >> 6, lane = t & 63, l15 = lane & 15, q4 = lane >> 4;
  int n0 = blockIdx.x * 16;
  // ---- build A rows w*4..w*4+3: Gx = [G_0..G_4 | z_root] ----
  for (int q = 0; q < 4; ++q) {
    int row = w * 4 + q, n = n0 + row;
    float g[5][3] = {};
    int beg = rowptr[n], end = rowptr[n + 1];
    for (int idx = beg; idx < end; ++idx) {
      int e = eord[idx];
      int s = ei[e];
      float4 u = eattr4[e];
#pragma unroll
      for (int m = 0; m < 3; ++m) {
        float zv = (float)z16in[(size_t)s * 192 + lane + 64 * m];
        g[0][m] += u.x * zv; g[1][m] += u.y * zv;
        g[2][m] += u.z * zv; g[3][m] += u.w * zv;
        g[4][m] += zv;
      }
    }
#pragma unroll
    for (int m = 0; m < 3; ++m) {
      int i = lane + 64 * m;
#pragma unroll
      for (int c = 0; c < 5; ++c) {
        int j = c * 192 + i;
        A_lds[((j >> 3) * 16 + row) * 8 + (j & 7)] = (_Float16)g[c][m];
      }
      int j = 960 + i;
      A_lds[((j >> 3) * 16 + row) * 8 + (j & 7)] = z16in[(size_t)n * 192 + i];
    }
  }
  __syncthreads();
  // ---- GEMM: cols w*48 + nt*16 + l15, K=1152 ----
  f32x4 acc[3] = {};
  const _Float16* bp = B2l + (((size_t)q4 * 192) + w * 48 + l15) * 8;
#pragma unroll 4
  for (int ks = 0; ks < 36; ++ks) {
    half8 av = *(const half8*)(A_lds + (((ks * 4 + q4) * 16) + l15) * 8);
#pragma unroll
    for (int nt = 0; nt < 3; ++nt) {
      half8 bv = *(const half8*)(bp + ((size_t)ks * 4 * 192 + nt * 16) * 8);
      acc[nt] = __builtin_amdgcn_mfma_f32_16x16x32_f16(av, bv, acc[nt], 0, 0, 0);
    }
  }
  // ---- epilogue: v = acc + cb (+hprev); LN over 192 cols per row ----
  float v[3][4];
  float p1[4] = {0.f, 0.f, 0.f, 0.f}, p2[4] = {0.f, 0.f, 0.f, 0.f};
#pragma unroll
  for (int r = 0; r < 4; ++r) {
    int n = n0 + q4 * 4 + r;
#pragma unroll
    for (int nt = 0; nt < 3; ++nt) {
      int col = w * 48 + nt * 16 + l15;
      float xv = acc[nt][r] + cbv[col];
      if (l > 0) xv += hp[(size_t)n * 192 + col];
      if (l < 3) ho[(size_t)n * 192 + col] = xv;
      v[nt][r] = xv;
      p1[r] += xv; p2[r] += xv * xv;
    }
  }
#pragma unroll
  for (int off = 1; off < 16; off <<= 1)
#pragma unroll
    for (int r = 0; r < 4; ++r) {
      p1[r] += __shfl_xor(p1[r], off);
      p2[r] += __shfl_xor(p2[r], off);
    }
  if (l15 == 0)
#pragma unroll
    for (int r = 0; r < 4; ++r) lnred[w][q4 * 4 + r] = make_float2(p1[r], p2[r]);
  __syncthreads();
  float zvals[3][4];
#pragma unroll
  for (int r = 0; r < 4; ++r) {
    int row = q4 * 4 + r;
    float s1 = 0.f, s2 = 0.f;
#pragma unroll
    for (int ww = 0; ww < 4; ++ww) { float2 pr = lnred[ww][row]; s1 += pr.x; s2 += pr.y; }
    float mu = s1 * (1.f / 192.f);
    float var = s2 * (1.f / 192.f) - mu * mu;
    float rcp = rsqrtf(var + 1e-5f);
#pragma unroll
    for (int nt = 0; nt < 3; ++nt) {
      int col = w * 48 + nt * 16 + l15;
      zvals[nt][r] = fmaxf((v[nt][r] - mu) * rcp * gg[col] + bb[col], 0.f);
    }
  }
  if (l < 3) {
#pragma unroll
    for (int r = 0; r < 4; ++r) {
      int n = n0 + q4 * 4 + r;
#pragma unroll
      for (int nt = 0; nt < 3; ++nt)
        z16out[(size_t)n * 192 + w * 48 + nt * 16 + l15] = (_Float16)zvals[nt][r];
    }
  } else {
    float po0[4] = {0.f, 0.f, 0.f, 0.f}, po1[4] = {0.f, 0.f, 0.f, 0.f};
#pragma unroll
    for (int r = 0; r < 4; ++r)
#pragma unroll
      for (int nt = 0; nt < 3; ++nt) {
        int col = w * 48 + nt * 16 + l15;
        po0[r] += zvals[nt][r] * out_w[col * 2];
        po1[r] += zvals[nt][r] * out_w[col * 2 + 1];
      }
#pragma unroll
    for (int off = 1; off < 16; off <<= 1)
#pragma unroll
      for (int r = 0; r < 4; ++r) {
        po0[r] += __shfl_xor(po0[r], off);
        po1[r] += __shfl_xor(po1[r], off);
      }
    if (l15 == 0)
#pragma unroll
      for (int r = 0; r < 4; ++r) outred[w][q4 * 4 + r] = make_float2(po0[r], po1[r]);
    __syncthreads();
    if (t < 32) {
      int row = t >> 1, c = t & 1;
      float s = 0.f;
#pragma unroll
      for (int ww = 0; ww < 4; ++ww) { float2 pr = outred[ww][row]; s += (c == 0) ? pr.x : pr.y; }
      outp[(n0 + row) * 2 + c] = s + out_b[c];
    }
  }
}

// ---------------- launch ----------------
extern "C" void kernel_launch(void* const* d_in, const int* in_sizes, int n_in,
                              void* d_out, int out_size, void* d_ws, size_t ws_size,
                              hipStream_t stream) {
  const float* x      = (const float*)d_in[0];
  const int*   ei     = (const int*)  d_in[1];
  const float* eattr  = (const float*)d_in[2];
  const float* cheb_w = (const float*)d_in[4];
  const float* cheb_b = (const float*)d_in[5];
  const float* eenc_w = (const float*)d_in[6];
  const float* eenc_b = (const float*)d_in[7];
  const float* nn1_w  = (const float*)d_in[8];
  const float* nn1_b  = (const float*)d_in[9];
  const float* nn2_w  = (const float*)d_in[10];
  const float* nn2_b  = (const float*)d_in[11];
  const float* root_w = (const float*)d_in[12];
  const float* conv_b = (const float*)d_in[13];
  const float* ln_g   = (const float*)d_in[14];
  const float* ln_bb  = (const float*)d_in[15];
  const float* out_w  = (const float*)d_in[16];
  const float* out_b  = (const float*)d_in[17];
  float* outp = (float*)d_out;
  (void)in_sizes; (void)n_in; (void)out_size; (void)ws_size;

  char* p = (char*)d_ws;
  _Float16* Btl = (_Float16*)p; p += (size_t)4 * 221184 * 2;   // 1.77 MB
  float* Tx     = (float*)p;    p += 5 * 4096 * 4;
  float* hA     = (float*)p;    p += 196608 * 4;
  float* hB     = (float*)p;    p += 196608 * 4;
  _Float16* z0  = (_Float16*)p; p += 196608 * 2;
  _Float16* zA  = (_Float16*)p; p += 196608 * 2;
  _Float16* zB  = (_Float16*)p; p += 196608 * 2;
  int* rowptr   = (int*)p;      p += 1056 * 4;
  int* eord     = (int*)p;      p += 2048 * 4;

  k_pb<<<dim3(74, 4), 256, 0, stream>>>(nn2_w, nn2_b, eenc_w, eenc_b, nn1_w, nn1_b,
                                        root_w, Btl, x, ei, Tx, rowptr, eord,
                                        cheb_w, cheb_b, z0);

  const _Float16* zin[4] = {z0, zA, zB, zA};
  _Float16* zout[4] = {zA, zB, zA, zA};       // zout[3] unused
  float* hout[4] = {hA, hB, hA, hA};          // hout[3] unused (l==3 skips ho)
  const float* hres[4] = {hA, hA, hB, hA};    // hres[0] unused
  for (int l = 0; l < 4; ++l) {
    k_lyr<<<64, 256, 0, stream>>>(zin[l], Btl + (size_t)l * 221184, ei,
                                  (const float4*)eattr, rowptr, eord, hres[l],
                                  conv_b + (size_t)l * 192,
                                  ln_g + (size_t)((l == 3) ? 0 : (l + 1)) * 192,
                                  ln_bb + (size_t)((l == 3) ? 0 : (l + 1)) * 192,
                                  hout[l], zout[l], out_w, out_b, outp, l);
  }
}

// Round 10
// 287.145 us; speedup vs baseline: 1.8539x; 1.8539x over previous
//
#include <hip/hip_runtime.h>
#include <stdint.h>

typedef _Float16 half8 __attribute__((ext_vector_type(8)));
typedef float f32x4 __attribute__((ext_vector_type(4)));

typedef const __attribute__((address_space(1))) void* gptr_t;
typedef __attribute__((address_space(3))) void* lptr_t;
static __device__ __forceinline__ void gll16(const void* g, void* l) {
  __builtin_amdgcn_global_load_lds((gptr_t)(unsigned long long)g,
                                   (lptr_t)(unsigned int)(unsigned long long)l,
                                   16, 0, 0);
}

// ---- k_pb: Btl = f16(M @ W2 + nn2_b); workers read W2 as 1KB-contiguous requests.
// grid (38,4): bx<36 workers (1024 cols, full K=192); bx==36 {y0 cheb, y1 CSR}; bx==37 root (y=l).
__global__ __launch_bounds__(256)
void k_pb(const float* __restrict__ nn2_w, const float* __restrict__ nn2_b,
          const float* __restrict__ eenc_w, const float* __restrict__ eenc_b,
          const float* __restrict__ nn1_w, const float* __restrict__ nn1_b,
          const float* __restrict__ root_w, _Float16* __restrict__ Btl,
          const float* __restrict__ x, const int* __restrict__ ei,
          float* __restrict__ Tx, int* __restrict__ rowptr, int* __restrict__ eord) {
  __shared__ __align__(16) float smem[33728];  // waves: 4 x 8buf x 4KB [0,32768); M [32768,33728)
  int t = threadIdx.x;
  if (blockIdx.x >= 36) {
    if (blockIdx.x == 36) {
      if (blockIdx.y == 0) {
        // ---- Chebyshev chain (r5/r7/r8-verified) ----
        float* cur = smem;
        float* yv = smem + 4096;
        float* deg = yv;
        for (int i = t; i < 1024; i += 256) deg[i] = 0.f;
        __syncthreads();
        for (int e = t; e < 2048; e += 256) atomicAdd(&deg[ei[e]], 1.f);
        __syncthreads();
        float wn[8];
#pragma unroll
        for (int i = 0; i < 8; ++i) {
          int e = t + 256 * i;
          int s = ei[e], d = ei[2048 + e];
          float ds = deg[s], dd = deg[d];
          float a = ds > 0.f ? 1.f / sqrtf(fmaxf(ds, 1.f)) : 0.f;
          float bb = dd > 0.f ? 1.f / sqrtf(fmaxf(dd, 1.f)) : 0.f;
          wn[i] = -a * bb;
        }
        __syncthreads();
        float4 prev[4];
#pragma unroll
        for (int q = 0; q < 4; ++q) {
          int i = t + 256 * q;
          float4 xv = ((const float4*)x)[i];
          ((float4*)cur)[i] = xv;
          ((float4*)Tx)[i] = xv;
        }
        __syncthreads();
        for (int rec = 0; rec < 4; ++rec) {
          for (int i = t; i < 4096; i += 256) yv[i] = 0.f;
          __syncthreads();
#pragma unroll
          for (int i = 0; i < 8; ++i) {
            int e = t + 256 * i;
            int s = ei[e], d = ei[2048 + e];
            float wv = wn[i];
#pragma unroll
            for (int c = 0; c < 4; ++c) atomicAdd(&yv[d * 4 + c], wv * cur[s * 4 + c]);
          }
          __syncthreads();
          float a = rec ? 2.f : 1.f;
#pragma unroll
          for (int q = 0; q < 4; ++q) {
            int i = t + 256 * q;
            float4 y4 = ((float4*)yv)[i];
            float4 c4 = ((float4*)cur)[i];
            float4 n4;
            n4.x = a * y4.x - (rec ? prev[q].x : 0.f);
            n4.y = a * y4.y - (rec ? prev[q].y : 0.f);
            n4.z = a * y4.z - (rec ? prev[q].z : 0.f);
            n4.w = a * y4.w - (rec ? prev[q].w : 0.f);
            prev[q] = c4;
            ((float4*)cur)[i] = n4;
            ((float4*)(Tx + (rec + 1) * 4096))[i] = n4;
          }
          __syncthreads();
        }
      } else if (blockIdx.y == 1) {
        // ---- CSR by dst (verified) ----
        int* cnt = (int*)smem;
        int* rp  = (int*)smem + 1024;
        int* wtot = (int*)smem + 2048;
        int lane = t & 63, wv = t >> 6;
        for (int i = t; i < 1024; i += 256) cnt[i] = 0;
        __syncthreads();
        for (int e = t; e < 2048; e += 256) atomicAdd(&cnt[ei[2048 + e]], 1);
        __syncthreads();
        int c0 = cnt[t * 4], c1 = cnt[t * 4 + 1], c2 = cnt[t * 4 + 2], c3 = cnt[t * 4 + 3];
        int s = c0 + c1 + c2 + c3;
        int inc = s;
#pragma unroll
        for (int off = 1; off < 64; off <<= 1) {
          int u = __shfl_up(inc, off);
          if (lane >= off) inc += u;
        }
        if (lane == 63) wtot[wv] = inc;
        __syncthreads();
        int woff = 0;
#pragma unroll
        for (int j = 0; j < 4; ++j) if (j < wv) woff += wtot[j];
        int excl = woff + inc - s;
        int4 r4; r4.x = excl; r4.y = excl + c0; r4.z = excl + c0 + c1; r4.w = excl + c0 + c1 + c2;
        *(int4*)(rowptr + t * 4) = r4;
        if (t == 0) rowptr[1024] = 2048;
        rp[t * 4] = r4.x; rp[t * 4 + 1] = r4.y; rp[t * 4 + 2] = r4.z; rp[t * 4 + 3] = r4.w;
        __syncthreads();
        for (int e = t; e < 2048; e += 256) {
          int d = ei[2048 + e];
          int slot = atomicAdd(&rp[d], 1);
          eord[slot] = e;
        }
      }
      return;
    }
    // ---- bx==37: root staging, B rows 960..1151 for layer by ----
    int l = blockIdx.y;
    for (int idx = t; idx < 36864; idx += 256) {
      float v = root_w[(size_t)l * 36864 + idx];
      int i = idx / 192, o = idx - i * 192;
      Btl[(size_t)l * 221184 + (i >> 3) * 9216 + (size_t)(960 + o) * 8 + (i & 7)] = (_Float16)v;
    }
    return;
  }
  // ---- worker: wave = 256 cols; each gll16 = 1 row-segment of 1KB contiguous; 8-buf pipeline ----
  int w = t >> 6, lane = t & 63;
  int l = blockIdx.y;
  int wcol = blockIdx.x * 1024 + w * 256;
  const float* W2l = nn2_w + (size_t)l * 7077888;
  char* ldsbase = (char*)smem + w * 32768;
  f32x4 nb4 = *(const f32x4*)(nn2_b + (size_t)l * 36864 + wcol + 4 * lane);

#define ISSUE(tile)                                                             \
  {                                                                             \
    _Pragma("unroll")                                                           \
    for (int r = 0; r < 4; ++r) {                                               \
      int row = (tile) * 4 + r;                                                 \
      gll16((const char*)(W2l + (size_t)row * 36864 + wcol) + lane * 16,        \
            ldsbase + ((tile) & 7) * 4096 + r * 1024 + lane * 16);              \
    }                                                                           \
  }

  ISSUE(0); ISSUE(1); ISSUE(2); ISSUE(3); ISSUE(4); ISSUE(5); ISSUE(6);
  // M[l] build (L3-absorbed redundancy, r5-proven); overlaps the prefetch latency
  if (t < 192) {
    float a0 = 0.f, a1 = 0.f, a2 = 0.f, a3 = 0.f, a4 = 0.f;
    const float* nw = nn1_w + (size_t)l * 36864 + t;
    for (int k = 0; k < 192; ++k) {
      float nv = nw[(size_t)k * 192];
      a0 += eenc_w[k] * nv;
      a1 += eenc_w[192 + k] * nv;
      a2 += eenc_w[384 + k] * nv;
      a3 += eenc_w[576 + k] * nv;
      a4 += eenc_b[k] * nv;
    }
    smem[32768 + t] = a0; smem[32960 + t] = a1; smem[33152 + t] = a2;
    smem[33344 + t] = a3; smem[33536 + t] = a4 + nn1_b[l * 192 + t];
  }
  __syncthreads();  // publishes M (and drains prologue prefetch)

  f32x4 a[5] = {};
  const float* Ms = smem + 32768;
  for (int tile = 0; tile < 48; ++tile) {
    if (tile < 41) ISSUE(tile + 7);
    if (tile < 41)       asm volatile("s_waitcnt vmcnt(28)" ::: "memory");
    else if (tile == 41) asm volatile("s_waitcnt vmcnt(24)" ::: "memory");
    else if (tile == 42) asm volatile("s_waitcnt vmcnt(20)" ::: "memory");
    else if (tile == 43) asm volatile("s_waitcnt vmcnt(16)" ::: "memory");
    else if (tile == 44) asm volatile("s_waitcnt vmcnt(12)" ::: "memory");
    else if (tile == 45) asm volatile("s_waitcnt vmcnt(8)" ::: "memory");
    else if (tile == 46) asm volatile("s_waitcnt vmcnt(4)" ::: "memory");
    else                 asm volatile("s_waitcnt vmcnt(0)" ::: "memory");
    const float* wb = (const float*)(ldsbase) + (tile & 7) * 1024;
    const float* Mt = Ms + tile * 4;
#pragma unroll
    for (int r = 0; r < 4; ++r) {
      f32x4 wv = *(const f32x4*)(wb + r * 256 + 4 * lane);
#pragma unroll
      for (int c = 0; c < 5; ++c) a[c] += Mt[c * 192 + r] * wv;
    }
  }
#undef ISSUE
  a[4] += nb4;
#pragma unroll
  for (int cc = 0; cc < 4; ++cc) {
    int col = wcol + 4 * lane + cc;
    int i = col / 192, o = col - i * 192;
    _Float16* B0 = Btl + (size_t)l * 221184 + (i >> 3) * 9216 + (i & 7);
#pragma unroll
    for (int c = 0; c < 5; ++c)
      B0[(size_t)(c * 192 + o) * 8] = (_Float16)a[c][cc];
  }
}

// ---- Y = z16 @ B (1024x1152, K=192); layer 0 builds its A-tile from Tx (cheb_out) in LDS ----
__global__ __launch_bounds__(256)
void k_y(const _Float16* __restrict__ z16, const _Float16* __restrict__ Btl,
         float* __restrict__ Y, const float* __restrict__ Tx,
         const float* __restrict__ cheb_w, const float* __restrict__ cheb_b, int layer) {
  __shared__ __align__(16) _Float16 Als[12288];  // 24 ck x 64 rows x 8 halfs (layer==0 only)
  int t = threadIdx.x;
  int w = t >> 6, lane = t & 63, l15 = lane & 15, q4 = lane >> 4;
  int e0 = blockIdx.x * 64, cb = blockIdx.y;
  if (layer == 0) {
#pragma unroll
    for (int it = 0; it < 6; ++it) {
      int u = it * 256 + t;
      int row = u & 63, ck = u >> 6;
      int n = e0 + row;
      float tv[5][4];
#pragma unroll
      for (int k = 0; k < 5; ++k) {
        float4 t4 = ((const float4*)(Tx + k * 4096))[n];
        tv[k][0] = t4.x; tv[k][1] = t4.y; tv[k][2] = t4.z; tv[k][3] = t4.w;
      }
      union { _Float16 h[8]; uint4 v; } u8;
#pragma unroll
      for (int j = 0; j < 8; ++j) {
        int o = ck * 8 + j;
        float acc = cheb_b[o];
#pragma unroll
        for (int k = 0; k < 5; ++k)
#pragma unroll
          for (int c = 0; c < 4; ++c)
            acc += tv[k][c] * cheb_w[(k * 4 + c) * 192 + o];
        u8.h[j] = (_Float16)acc;
      }
      *(uint4*)(Als + (size_t)u * 8) = u8.v;
    }
    __syncthreads();
  }
  const _Float16* Bt = Btl + (size_t)layer * 221184;
  const _Float16* ap = z16 + (((size_t)q4 * 1024) + e0 + w * 16 + l15) * 8;
  const _Float16* bp = Bt + (((size_t)q4 * 1152) + cb * 192 + l15) * 8;
  f32x4 acc[12] = {};
#pragma unroll
  for (int ks = 0; ks < 6; ++ks) {
    half8 av;
    if (layer == 0)
      av = *(const half8*)(Als + (((size_t)(ks * 4 + q4) * 64) + w * 16 + l15) * 8);
    else
      av = *(const half8*)(ap + (size_t)ks * 4 * 1024 * 8);
#pragma unroll
    for (int nt = 0; nt < 12; ++nt) {
      half8 bv = *(const half8*)(bp + (size_t)ks * 4 * 1152 * 8 + nt * 16 * 8);
      acc[nt] = __builtin_amdgcn_mfma_f32_16x16x32_f16(av, bv, acc[nt], 0, 0, 0);
    }
  }
#pragma unroll
  for (int nt = 0; nt < 12; ++nt) {
    int col = cb * 192 + nt * 16 + l15;
#pragma unroll
    for (int r = 0; r < 4; ++r) {
      int row = e0 + w * 16 + q4 * 4 + r;
      Y[(size_t)row * 1152 + col] = acc[nt][r];
    }
  }
}

// ---- gather by dst (CSR) + root + bias + residual + LN + relu (+ final for l==3) ----
__global__ __launch_bounds__(256)
void k_gn(const int* __restrict__ ei, const float* __restrict__ eattr,
          const int* __restrict__ rowptr, const int* __restrict__ eord,
          const float* __restrict__ Y, const float* __restrict__ hp,
          const float* __restrict__ cbv, const float* __restrict__ gg,
          const float* __restrict__ bb, float* __restrict__ ho,
          _Float16* __restrict__ zo, const float* __restrict__ out_w,
          const float* __restrict__ out_b, float* __restrict__ outp, int l) {
  int t = threadIdx.x, w = t >> 6, lane = t & 63;
  int n = blockIdx.x * 4 + w;
  int o0 = lane, o1 = lane + 64, o2 = lane + 128;
  float v0 = 0.f, v1 = 0.f, v2 = 0.f;
  int beg = rowptr[n], end = rowptr[n + 1];
  for (int idx = beg; idx < end; ++idx) {
    int e = eord[idx];
    int s = ei[e];
    float4 u = ((const float4*)eattr)[e];
    const float* yr = Y + (size_t)s * 1152;
    v0 += yr[o0] * u.x + yr[192 + o0] * u.y + yr[384 + o0] * u.z + yr[576 + o0] * u.w + yr[768 + o0];
    v1 += yr[o1] * u.x + yr[192 + o1] * u.y + yr[384 + o1] * u.z + yr[576 + o1] * u.w + yr[768 + o1];
    v2 += yr[o2] * u.x + yr[192 + o2] * u.y + yr[384 + o2] * u.z + yr[576 + o2] * u.w + yr[768 + o2];
  }
  const float* yn = Y + (size_t)n * 1152 + 960;
  v0 += yn[o0] + cbv[o0]; v1 += yn[o1] + cbv[o1]; v2 += yn[o2] + cbv[o2];
  if (l > 0) {
    v0 += hp[n * 192 + o0]; v1 += hp[n * 192 + o1]; v2 += hp[n * 192 + o2];
  }
  if (l < 3) {
    ho[n * 192 + o0] = v0; ho[n * 192 + o1] = v1; ho[n * 192 + o2] = v2;
  }
  float s1 = v0 + v1 + v2, s2 = v0 * v0 + v1 * v1 + v2 * v2;
#pragma unroll
  for (int off = 32; off >= 1; off >>= 1) {
    s1 += __shfl_xor(s1, off);
    s2 += __shfl_xor(s2, off);
  }
  float mu = s1 * (1.f / 192.f);
  float var = s2 * (1.f / 192.f) - mu * mu;
  float rcp = rsqrtf(var + 1e-5f);
  float z0v = fmaxf((v0 - mu) * rcp * gg[o0] + bb[o0], 0.f);
  float z1v = fmaxf((v1 - mu) * rcp * gg[o1] + bb[o1], 0.f);
  float z2v = fmaxf((v2 - mu) * rcp * gg[o2] + bb[o2], 0.f);
  if (l < 3) {
    zo[((size_t)(o0 >> 3) * 1024 + n) * 8 + (o0 & 7)] = (_Float16)z0v;
    zo[((size_t)(o1 >> 3) * 1024 + n) * 8 + (o1 & 7)] = (_Float16)z1v;
    zo[((size_t)(o2 >> 3) * 1024 + n) * 8 + (o2 & 7)] = (_Float16)z2v;
  } else {
    float a0 = z0v * out_w[o0 * 2] + z1v * out_w[o1 * 2] + z2v * out_w[o2 * 2];
    float a1 = z0v * out_w[o0 * 2 + 1] + z1v * out_w[o1 * 2 + 1] + z2v * out_w[o2 * 2 + 1];
#pragma unroll
    for (int off = 32; off >= 1; off >>= 1) {
      a0 += __shfl_xor(a0, off);
      a1 += __shfl_xor(a1, off);
    }
    if (lane == 0) {
      outp[n * 2] = a0 + out_b[0];
      outp[n * 2 + 1] = a1 + out_b[1];
    }
  }
}

// ---------------- launch ----------------
extern "C" void kernel_launch(void* const* d_in, const int* in_sizes, int n_in,
                              void* d_out, int out_size, void* d_ws, size_t ws_size,
                              hipStream_t stream) {
  const float* x      = (const float*)d_in[0];
  const int*   ei     = (const int*)  d_in[1];
  const float* eattr  = (const float*)d_in[2];
  const float* cheb_w = (const float*)d_in[4];
  const float* cheb_b = (const float*)d_in[5];
  const float* eenc_w = (const float*)d_in[6];
  const float* eenc_b = (const float*)d_in[7];
  const float* nn1_w  = (const float*)d_in[8];
  const float* nn1_b  = (const float*)d_in[9];
  const float* nn2_w  = (const float*)d_in[10];
  const float* nn2_b  = (const float*)d_in[11];
  const float* root_w = (const float*)d_in[12];
  const float* conv_b = (const float*)d_in[13];
  const float* ln_g   = (const float*)d_in[14];
  const float* ln_bb  = (const float*)d_in[15];
  const float* out_w  = (const float*)d_in[16];
  const float* out_b  = (const float*)d_in[17];
  float* outp = (float*)d_out;
  (void)in_sizes; (void)n_in; (void)out_size; (void)ws_size;

  char* p = (char*)d_ws;
  _Float16* Btl = (_Float16*)p; p += (size_t)4 * 221184 * 2;   // 1.77 MB
  float* Tx     = (float*)p;    p += 5 * 4096 * 4;
  float* Y      = (float*)p;    p += (size_t)1024 * 1152 * 4;  // 4.7 MB
  float* hA     = (float*)p;    p += 196608 * 4;
  float* hB     = (float*)p;    p += 196608 * 4;
  _Float16* zA  = (_Float16*)p; p += 196608 * 2;
  _Float16* zB  = (_Float16*)p; p += 196608 * 2;
  int* rowptr   = (int*)p;      p += 1056 * 4;
  int* eord     = (int*)p;      p += 2048 * 4;

  k_pb<<<dim3(38, 4), 256, 0, stream>>>(nn2_w, nn2_b, eenc_w, eenc_b, nn1_w, nn1_b,
                                        root_w, Btl, x, ei, Tx, rowptr, eord);

  const _Float16* zin[4] = {zA, zA, zB, zA};  // zin[0] unused (layer 0 builds A from Tx)
  _Float16* zout[4] = {zA, zB, zA, zA};       // zout[3] unused
  float* hout[4] = {hA, hB, hA, hA};          // hout[3] unused
  const float* hres[4] = {hA, hA, hB, hA};    // hres[0] unused
  for (int l = 0; l < 4; ++l) {
    k_y<<<dim3(16, 6), 256, 0, stream>>>(zin[l], Btl, Y, Tx, cheb_w, cheb_b, l);
    k_gn<<<256, 256, 0, stream>>>(ei, eattr, rowptr, eord, Y, hres[l],
                                  conv_b + (size_t)l * 192,
                                  ln_g + (size_t)((l == 3) ? 0 : (l + 1)) * 192,
                                  ln_bb + (size_t)((l == 3) ? 0 : (l + 1)) * 192,
                                  hout[l], zout[l], out_w, out_b, outp, l);
  }
}